// Round 4
// baseline (1181.201 us; speedup 1.0000x reference)
//
#include <hip/hip_runtime.h>
#include <float.h>

#define BB 16
#define NN 4096
#define CC 64
#define KNN 32

// ---------------------------------------------------------------------------
// Kernel 1: KNN replicating the np reference's fp32 arithmetic, VARIANT V2
// (XLA-CPU / Eigen K=3 dot_general lowering):
//   dot  = fma(z_q,z_c, fma(y_q,y_c, x_q*x_c))     <- sequential FMA chain
//   xx   = ((x*x + y*y) + z*z)                      <- plain rn (square+reduce
//                                                      fusion emits no fma)
//   pd   = ((dot+dot) - xx_q) - xx_c                <- left-assoc rn subtracts
// Largest pd = nearest. One thread per query; batch xyz in LDS (float4 with
// xx in .w, 64 KB). Top-32 largest in a descending sorted register array;
// insert via med3 (1 VALU/slot). Pass 2 re-scans and emits indices with
// pd > T always, pd == T by lowest-index-first within tie budget
// (= lax.top_k tie semantics; only the SET matters downstream).
// Variant journal: V1 seq-rn = 0.516, exact-fp64 = 0.2266, V2 = this round.
// ---------------------------------------------------------------------------
__global__ __launch_bounds__(256) void knn_kernel(const float* __restrict__ xyz,
                                                  int* __restrict__ idx_out) {
#pragma clang fp contract(off)
    __shared__ float4 pts[NN];  // 64 KB: x,y,z,xx
    const int tid = threadIdx.x;
    const int blk = blockIdx.x;
    const int b = blk >> 4;                      // 16 blocks per batch
    const int q = ((blk & 15) << 8) | tid;       // query index within batch
    const float* xb = xyz + (size_t)b * (3 * NN);

    for (int p = tid; p < NN; p += 256) {
        float x = xb[p];
        float y = xb[NN + p];
        float z = xb[2 * NN + p];
        float xx = ((x * x) + (y * y)) + (z * z);  // rn, no fma (pragma)
        pts[p] = make_float4(x, y, z, xx);
    }
    __syncthreads();

    const float4 qp = pts[q];
    float heap[KNN];  // sorted descending; heap[31] = current threshold
#pragma unroll
    for (int j = 0; j < KNN; ++j) heap[j] = -FLT_MAX;

    for (int i = 0; i < NN; ++i) {
        float4 cp = pts[i];
        float dot = __builtin_fmaf(qp.z, cp.z,
                    __builtin_fmaf(qp.y, cp.y, qp.x * cp.x));  // V2 fma chain
        float pd = ((dot + dot) - qp.w) - cp.w;                // rn, left-assoc
        if (pd > heap[KNN - 1]) {
            // predicated sorted insert: heap[j] = median(pd, heap[j], heap[j-1])
#pragma unroll
            for (int j = KNN - 1; j >= 1; --j)
                heap[j] = __builtin_amdgcn_fmed3f(pd, heap[j], heap[j - 1]);
            heap[0] = fmaxf(heap[0], pd);
        }
    }

    const float T = heap[KNN - 1];  // 32nd-largest pd under V2 arithmetic
    int cs = 0;
#pragma unroll
    for (int j = 0; j < KNN - 1; ++j) cs += (heap[j] > T) ? 1 : 0;
    int budget = KNN - cs;  // ties at T to accept, lowest index first
    int cnt = 0;
    int* outp = idx_out + ((size_t)(b * NN + q)) * KNN;
    for (int i = 0; i < NN && cnt < KNN; ++i) {
        float4 cp = pts[i];
        float dot = __builtin_fmaf(qp.z, cp.z,
                    __builtin_fmaf(qp.y, cp.y, qp.x * cp.x));
        float pd = ((dot + dot) - qp.w) - cp.w;
        if (pd > T) {
            outp[cnt++] = i;
        } else if (pd == T && budget > 0) {
            outp[cnt++] = i;
            --budget;
        }
    }
}

// ---------------------------------------------------------------------------
// Kernel 2: neighbor gather -> per-(q,c) max/min offset + block sum(off^2)
// accumulated in fp64 (sigma exactness). One wave per query, lane = channel.
// ---------------------------------------------------------------------------
__global__ __launch_bounds__(256) void gather_minmax_kernel(
        const float* __restrict__ feats, const int* __restrict__ idx_in,
        float* __restrict__ mx_buf, float* __restrict__ mn_buf,
        double* __restrict__ partials) {
    const int tid = threadIdx.x;
    const int w = tid >> 6;
    const int lane = tid & 63;
    const int q = blockIdx.x * 4 + w;  // global query 0..65535
    const int b = q >> 12;
    const float* fb = feats + (size_t)b * (NN * CC);
    const float center = feats[(size_t)q * CC + lane];
    const int* ip = idx_in + (size_t)q * KNN;

    float mx = -FLT_MAX, mn = FLT_MAX;
    double ss = 0.0;
#pragma unroll 4
    for (int k = 0; k < KNN; ++k) {
        int nb = ip[k];
        float v = fb[(size_t)nb * CC + lane];
        float off = v - center;  // fp32 rn == ref's offset
        mx = fmaxf(mx, off);
        mn = fminf(mn, off);
        double od = (double)off;
        ss = fma(od, od, ss);
    }
    mx_buf[(size_t)q * CC + lane] = mx;
    mn_buf[(size_t)q * CC + lane] = mn;

#pragma unroll
    for (int o = 32; o >= 1; o >>= 1) ss += __shfl_down(ss, o, 64);
    __shared__ double wsum[4];
    if (lane == 0) wsum[w] = ss;
    __syncthreads();
    if (tid == 0) partials[blockIdx.x] = (wsum[0] + wsum[1]) + (wsum[2] + wsum[3]);
}

// ---------------------------------------------------------------------------
// Kernel 2.5: reduce 16384 block partials -> sigma (mean over 2^27, fp64)
// ---------------------------------------------------------------------------
__global__ __launch_bounds__(256) void sigma_kernel(const double* __restrict__ partials,
                                                    float* __restrict__ sigma) {
    __shared__ double red[256];
    double s = 0.0;
    for (int i = threadIdx.x; i < 16384; i += 256) s += partials[i];
    red[threadIdx.x] = s;
    __syncthreads();
    for (int o = 128; o >= 1; o >>= 1) {
        if (threadIdx.x < o) red[threadIdx.x] += red[threadIdx.x + o];
        __syncthreads();
    }
    if (threadIdx.x == 0) sigma[0] = (float)(red[0] * (1.0 / 134217728.0));  // /2^27
}

// ---------------------------------------------------------------------------
// Kernel 3: pooled[q,c] = ((alpha>=0 ? mx : mn) / (sigma+eps)) * alpha + beta
// fp32 throughout to match the ref's elementwise rounding; fp32 division by
// positive s is monotone, so max-then-divide == divide-then-max exactly.
// ---------------------------------------------------------------------------
__global__ __launch_bounds__(256) void finalize_kernel(
        const float* __restrict__ mx_buf, const float* __restrict__ mn_buf,
        const float* __restrict__ alpha, const float* __restrict__ beta,
        const float* __restrict__ sigma, float* __restrict__ out) {
#pragma clang fp contract(off)
    const int e = blockIdx.x * 256 + threadIdx.x;  // 0..4194303
    const int c = e & (CC - 1);
    const float s = sigma[0] + 1e-5f;
    const float a = alpha[c];
    const float bt = beta[c];
    const float off = (a >= 0.f) ? mx_buf[e] : mn_buf[e];
    const float t = off / s;
    out[e] = (t * a) + bt;
}

extern "C" void kernel_launch(void* const* d_in, const int* in_sizes, int n_in,
                              void* d_out, int out_size, void* d_ws, size_t ws_size,
                              hipStream_t stream) {
    (void)in_sizes; (void)n_in; (void)out_size; (void)ws_size;
    const float* xyz   = (const float*)d_in[0];  // [16,3,4096]
    const float* feats = (const float*)d_in[1];  // [16,4096,64]
    const float* alpha = (const float*)d_in[2];  // [64]
    const float* beta  = (const float*)d_in[3];  // [64]
    float* out = (float*)d_out;                  // [16,4096,64]

    char* ws = (char*)d_ws;
    int*    idx_buf  = (int*)ws;                     // 65536*32*4  = 8,388,608 B
    float*  mx_buf   = (float*)(ws + 8388608);       // 16,777,216 B
    float*  mn_buf   = (float*)(ws + 25165824);      // 16,777,216 B
    double* partials = (double*)(ws + 41943040);     // 16384*8 = 131,072 B
    float*  sigma    = (float*)(ws + 42074112);      // 4 B

    knn_kernel<<<BB * (NN / 256), 256, 0, stream>>>(xyz, idx_buf);
    gather_minmax_kernel<<<(BB * NN) / 4, 256, 0, stream>>>(feats, idx_buf, mx_buf,
                                                            mn_buf, partials);
    sigma_kernel<<<1, 256, 0, stream>>>(partials, sigma);
    finalize_kernel<<<(BB * NN * CC) / 256, 256, 0, stream>>>(mx_buf, mn_buf, alpha,
                                                              beta, sigma, out);
}

// Round 5
// 559.393 us; speedup vs baseline: 2.1116x; 2.1116x over previous
//
#include <hip/hip_runtime.h>
#include <float.h>

#define BB 16
#define NN 4096
#define CC 64
#define KNN 32
#define NPART 4
#define PSZ 1024   // NN / NPART
#define NQ 65536   // BB * NN

// ===========================================================================
// KNN, reference arithmetic VARIANT V2 (verified bit-compatible in R4):
//   dot = fma(z,z', fma(y,y', x*x'));  xx = ((x*x + y*y) + z*z)  [rn, no fma]
//   pd  = ((dot+dot) - xx_q) - xx_c    [left-assoc rn]
// Largest pd = nearest. Selection set must match fp32-V2 top-32 exactly.
//
// R5 restructure: 1024 total waves (1 wave/SIMD, VALUBusy 28%) was the
// bottleneck. Split each query's candidate scan over NPART=4 partitions:
//   A) select: per (query, partition) branchless med3 top-32 VALUES -> global
//   B) merge:  exact 4-way merge of sorted lists -> T (32nd largest) +
//              per-partition take count n_p / strict count s_p / base offset
//              (first-max-wins on ties == partition order == index order,
//               matching lax.top_k stability; only the SET matters downstream)
//   C) emit:   re-scan partition with T, write indices (strict then ties)
// ===========================================================================

// --------------------------------------------------------------------------
// A: grid 1024 = (b<<6)|(g<<2)|p, 256 thr = 256 queries. LDS = 16KB partition.
// --------------------------------------------------------------------------
__global__ __launch_bounds__(256) void knn_select_kernel(
        const float* __restrict__ xyz, float* __restrict__ val_buf) {
#pragma clang fp contract(off)
    __shared__ float4 pts[PSZ];  // 16 KB: x,y,z,xx
    const int tid = threadIdx.x;
    const int blk = blockIdx.x;
    const int p = blk & 3;
    const int g = (blk >> 2) & 15;
    const int b = blk >> 6;
    const float* xb = xyz + (size_t)b * (3 * NN);

    for (int j = tid; j < PSZ; j += 256) {
        int i = (p << 10) | j;
        float x = xb[i], y = xb[NN + i], z = xb[2 * NN + i];
        float xx = ((x * x) + (y * y)) + (z * z);  // rn (contract off)
        pts[j] = make_float4(x, y, z, xx);
    }
    const int q = (g << 8) | tid;  // query within batch
    const float qx = xb[q], qy = xb[NN + q], qz = xb[2 * NN + q];
    const float qxx = ((qx * qx) + (qy * qy)) + (qz * qz);
    __syncthreads();

    float heap[KNN];  // sorted descending
#pragma unroll
    for (int t = 0; t < KNN; ++t) heap[t] = -FLT_MAX;

    for (int j = 0; j < PSZ; ++j) {
        float4 cp = pts[j];
        float dot = __builtin_fmaf(qz, cp.z, __builtin_fmaf(qy, cp.y, qx * cp.x));
        float pd = ((dot + dot) - qxx) - cp.w;
        // branchless sorted insert (med3 is a correct no-op when pd too small)
#pragma unroll
        for (int t = KNN - 1; t >= 1; --t)
            heap[t] = __builtin_amdgcn_fmed3f(pd, heap[t], heap[t - 1]);
        heap[0] = fmaxf(heap[0], pd);
    }

    const int qg = (b << 12) | q;  // global query
#pragma unroll
    for (int t = 0; t < KNN; ++t)
        val_buf[(size_t)((p * KNN + t)) * NQ + qg] = heap[t];  // coalesced
}

// --------------------------------------------------------------------------
// B: one thread per query; 64-thr blocks; lists staged to LDS (pad 129).
// --------------------------------------------------------------------------
__global__ __launch_bounds__(64) void knn_merge_kernel(
        const float* __restrict__ val_buf, float* __restrict__ T_buf,
        int* __restrict__ pack_buf) {
    __shared__ float lv[64 * 129];  // 33 KB
    const int tid = threadIdx.x;
    const int qg = blockIdx.x * 64 + tid;
    float* my = lv + tid * 129;
    for (int t = 0; t < 128; ++t) my[t] = val_buf[(size_t)t * NQ + qg];

    int i0 = 0, i1 = 0, i2 = 0, i3 = 0;
    float T = -FLT_MAX;
    for (int s = 0; s < 32; ++s) {
        float v0 = (i0 < 32) ? my[i0] : -FLT_MAX;
        float v1 = (i1 < 32) ? my[32 + i1] : -FLT_MAX;
        float v2 = (i2 < 32) ? my[64 + i2] : -FLT_MAX;
        float v3 = (i3 < 32) ? my[96 + i3] : -FLT_MAX;
        float best = v0; int bp = 0;
        if (v1 > best) { best = v1; bp = 1; }   // strict: ties keep lower p
        if (v2 > best) { best = v2; bp = 2; }
        if (v3 > best) { best = v3; bp = 3; }
        T = best;
        i0 += (bp == 0); i1 += (bp == 1); i2 += (bp == 2); i3 += (bp == 3);
    }
    int s0 = 0, s1 = 0, s2 = 0, s3 = 0;
    for (int j = 0; j < 32; ++j) {
        s0 += (my[j] > T); s1 += (my[32 + j] > T);
        s2 += (my[64 + j] > T); s3 += (my[96 + j] > T);
    }
    T_buf[qg] = T;
    int base = 0;
    pack_buf[qg * 4 + 0] = base | (s0 << 8) | (i0 << 16); base += i0;
    pack_buf[qg * 4 + 1] = base | (s1 << 8) | (i1 << 16); base += i1;
    pack_buf[qg * 4 + 2] = base | (s2 << 8) | (i2 << 16); base += i2;
    pack_buf[qg * 4 + 3] = base | (s3 << 8) | (i3 << 16);
}

// --------------------------------------------------------------------------
// C: same shape as A; re-scan with T, emit batch-local indices.
// --------------------------------------------------------------------------
__global__ __launch_bounds__(256) void knn_emit_kernel(
        const float* __restrict__ xyz, const float* __restrict__ T_buf,
        const int* __restrict__ pack_buf, int* __restrict__ idx_out) {
#pragma clang fp contract(off)
    __shared__ float4 pts[PSZ];
    const int tid = threadIdx.x;
    const int blk = blockIdx.x;
    const int p = blk & 3;
    const int g = (blk >> 2) & 15;
    const int b = blk >> 6;
    const float* xb = xyz + (size_t)b * (3 * NN);

    for (int j = tid; j < PSZ; j += 256) {
        int i = (p << 10) | j;
        float x = xb[i], y = xb[NN + i], z = xb[2 * NN + i];
        float xx = ((x * x) + (y * y)) + (z * z);
        pts[j] = make_float4(x, y, z, xx);
    }
    const int q = (g << 8) | tid;
    const float qx = xb[q], qy = xb[NN + q], qz = xb[2 * NN + q];
    const float qxx = ((qx * qx) + (qy * qy)) + (qz * qz);
    __syncthreads();

    const int qg = (b << 12) | q;
    const float T = T_buf[qg];
    const int pk = pack_buf[qg * 4 + p];
    int slot = pk & 255;
    const int sp = (pk >> 8) & 255;
    const int np = (pk >> 16) & 255;
    int tie_slot = slot + sp;
    const int tie_end = slot + np;
    int* outp = idx_out + (size_t)qg * KNN;

    for (int j = 0; j < PSZ; ++j) {
        float4 cp = pts[j];
        float dot = __builtin_fmaf(qz, cp.z, __builtin_fmaf(qy, cp.y, qx * cp.x));
        float pd = ((dot + dot) - qxx) - cp.w;
        if (pd > T) {
            outp[slot++] = (p << 10) | j;
        } else if (pd == T && tie_slot < tie_end) {
            outp[tie_slot++] = (p << 10) | j;
        }
    }
}

// --------------------------------------------------------------------------
// gather: one wave per query, lane = channel; fp64 sigma accumulation.
// --------------------------------------------------------------------------
__global__ __launch_bounds__(256) void gather_minmax_kernel(
        const float* __restrict__ feats, const int* __restrict__ idx_in,
        float* __restrict__ mx_buf, float* __restrict__ mn_buf,
        double* __restrict__ partials) {
    const int tid = threadIdx.x;
    const int w = tid >> 6;
    const int lane = tid & 63;
    const int q = blockIdx.x * 4 + w;
    const int b = q >> 12;
    const float* fb = feats + (size_t)b * (NN * CC);
    const float center = feats[(size_t)q * CC + lane];
    const int* ip = idx_in + (size_t)q * KNN;

    float mx = -FLT_MAX, mn = FLT_MAX;
    double ss = 0.0;
#pragma unroll 4
    for (int k = 0; k < KNN; ++k) {
        int nb = ip[k];
        float v = fb[(size_t)nb * CC + lane];
        float off = v - center;
        mx = fmaxf(mx, off);
        mn = fminf(mn, off);
        double od = (double)off;
        ss = fma(od, od, ss);
    }
    mx_buf[(size_t)q * CC + lane] = mx;
    mn_buf[(size_t)q * CC + lane] = mn;

#pragma unroll
    for (int o = 32; o >= 1; o >>= 1) ss += __shfl_down(ss, o, 64);
    __shared__ double wsum[4];
    if (lane == 0) wsum[w] = ss;
    __syncthreads();
    if (tid == 0) partials[blockIdx.x] = (wsum[0] + wsum[1]) + (wsum[2] + wsum[3]);
}

__global__ __launch_bounds__(256) void sigma_kernel(const double* __restrict__ partials,
                                                    float* __restrict__ sigma) {
    __shared__ double red[256];
    double s = 0.0;
    for (int i = threadIdx.x; i < 16384; i += 256) s += partials[i];
    red[threadIdx.x] = s;
    __syncthreads();
    for (int o = 128; o >= 1; o >>= 1) {
        if (threadIdx.x < o) red[threadIdx.x] += red[threadIdx.x + o];
        __syncthreads();
    }
    if (threadIdx.x == 0) sigma[0] = (float)(red[0] * (1.0 / 134217728.0));
}

__global__ __launch_bounds__(256) void finalize_kernel(
        const float* __restrict__ mx_buf, const float* __restrict__ mn_buf,
        const float* __restrict__ alpha, const float* __restrict__ beta,
        const float* __restrict__ sigma, float* __restrict__ out) {
#pragma clang fp contract(off)
    const int e = blockIdx.x * 256 + threadIdx.x;
    const int c = e & (CC - 1);
    const float s = sigma[0] + 1e-5f;
    const float a = alpha[c];
    const float bt = beta[c];
    const float off = (a >= 0.f) ? mx_buf[e] : mn_buf[e];
    const float t = off / s;
    out[e] = (t * a) + bt;
}

extern "C" void kernel_launch(void* const* d_in, const int* in_sizes, int n_in,
                              void* d_out, int out_size, void* d_ws, size_t ws_size,
                              hipStream_t stream) {
    (void)in_sizes; (void)n_in; (void)out_size; (void)ws_size;
    const float* xyz   = (const float*)d_in[0];  // [16,3,4096]
    const float* feats = (const float*)d_in[1];  // [16,4096,64]
    const float* alpha = (const float*)d_in[2];  // [64]
    const float* beta  = (const float*)d_in[3];  // [64]
    float* out = (float*)d_out;                  // [16,4096,64]

    char* ws = (char*)d_ws;
    // Layout (aliased — val_buf is dead before gather writes mx/mn):
    int*    idx_buf  = (int*)ws;                     // [0, 8MB)
    float*  val_buf  = (float*)(ws + 8388608);       // [8MB, 40MB)  65536*128*4
    float*  mx_buf   = (float*)(ws + 8388608);       // alias  [8MB, 24MB)
    float*  mn_buf   = (float*)(ws + 25165824);      // alias  [24MB, 40MB)
    float*  T_buf    = (float*)(ws + 41943040);      // [40MB, +256KB)
    int*    pack_buf = (int*)(ws + 42205184);        // [+1MB)
    double* partials = (double*)(ws + 43253760);     // 16384*8 = 128KB
    float*  sigma    = (float*)(ws + 43384832);

    knn_select_kernel<<<BB * 16 * NPART, 256, 0, stream>>>(xyz, val_buf);
    knn_merge_kernel<<<NQ / 64, 64, 0, stream>>>(val_buf, T_buf, pack_buf);
    knn_emit_kernel<<<BB * 16 * NPART, 256, 0, stream>>>(xyz, T_buf, pack_buf, idx_buf);
    gather_minmax_kernel<<<NQ / 4, 256, 0, stream>>>(feats, idx_buf, mx_buf,
                                                     mn_buf, partials);
    sigma_kernel<<<1, 256, 0, stream>>>(partials, sigma);
    finalize_kernel<<<(NQ * CC) / 256, 256, 0, stream>>>(mx_buf, mn_buf, alpha,
                                                         beta, sigma, out);
}